// Round 11
// baseline (11003.086 us; speedup 1.0000x reference)
//
#include <hip/hip_runtime.h>
#include <math.h>
#include <stdint.h>

#define EPS 1e-8f
#define FMAXV 3.402823466e38f

// ---------------- 3-D Morton grid parameters ----------------
#define GD3 32
#define NC3 (GD3 * GD3 * GD3)     // 32768 cells
#define BLO (-6.0f)
#define CS 0.375f                  // 12/32, exact; BLO + c*CS exact (multiples of 0.125)
#define INVCS 2.6666667f           // only monotone consistency needed
#define MARGIN 2e-4f               // >> max |frozen score - true dist^2| (~4e-5)
#define SLACK 1e-3f                // fp32 box-dist eval slack
#define RPAD 1e-4f                 // cell-range rounding pad

__device__ __forceinline__ int mcell(float x) {
    int c = (int)floorf((x - BLO) * INVCS);
    return min(max(c, 0), GD3 - 1);
}
__device__ __forceinline__ unsigned spread3(unsigned v) {
    v &= 0x3FFu;
    v = (v | (v << 16)) & 0x030000FFu;
    v = (v | (v << 8))  & 0x0300F00Fu;
    v = (v | (v << 4))  & 0x030C30C3u;
    v = (v | (v << 2))  & 0x09249249u;
    return v;
}
__device__ __forceinline__ unsigned mkey3(int cx, int cy, int cz) {
    return spread3((unsigned)cx) | (spread3((unsigned)cy) << 1) | (spread3((unsigned)cz) << 2);
}
__device__ __forceinline__ float finf() { return __uint_as_float(0x7f800000u); }

// Monotone float->uint key; (key_hi(d)<<32)|idx = lexicographic (d, idx)
// == jax.lax.top_k lowest-index tie-break (validated R8/R9/R10).
__device__ __forceinline__ unsigned key_hi(float d) {
    unsigned b = __float_as_uint(d);
    return (b & 0x80000000u) ? ~b : (b | 0x80000000u);
}
__device__ __forceinline__ float key_d(unsigned long long k) {
    unsigned h = (unsigned)(k >> 32);
    unsigned b = (h & 0x80000000u) ? (h & 0x7fffffffu) : ~h;
    return __uint_as_float(b);
}
__device__ __forceinline__ float bound3(unsigned long long k2) {
    return (k2 == ~0ULL) ? finf() : key_d(k2);
}
__device__ __forceinline__ void insert3k(unsigned long long k,
        unsigned long long& k0, unsigned long long& k1, unsigned long long& k2) {
    const bool c0 = k < k0, c1 = k < k1, c2 = k < k2;
    k2 = c1 ? k1 : (c2 ? k : k2);
    k1 = c0 ? k0 : (c1 ? k : k1);
    k0 = c0 ? k : k0;
}

// ---------------- build: histogram / hierarchical scan / scatter ----------------
__global__ void k_histM(const float* __restrict__ sp, int N,
                        const float* __restrict__ tp, int M,
                        int* __restrict__ scnt, int* __restrict__ qcnt) {
    int i = blockIdx.x * 256 + threadIdx.x;
    if (i < N) {
        atomicAdd(&scnt[mkey3(mcell(sp[3 * i]), mcell(sp[3 * i + 1]), mcell(sp[3 * i + 2]))], 1);
    } else if (i < N + M) {
        int j = i - N;
        atomicAdd(&qcnt[mkey3(mcell(tp[3 * j]), mcell(tp[3 * j + 1]), mcell(tp[3 * j + 2]))], 1);
    }
}

// 64 blocks: 0..31 source counters, 32..63 query counters.
__global__ __launch_bounds__(1024) void k_scanA2(int* __restrict__ scnt, int* __restrict__ qcnt,
                                                 int* __restrict__ soffs, int* __restrict__ qoffs,
                                                 int* __restrict__ bsum) {
    const int grp = blockIdx.x >> 5;
    const int blk = blockIdx.x & 31;
    int* cnt  = grp ? qcnt  : scnt;
    int* offs = grp ? qoffs : soffs;
    __shared__ int sh[1024];
    int i = blk * 1024 + threadIdx.x;
    int v = cnt[i];
    sh[threadIdx.x] = v;
    __syncthreads();
    for (int o = 1; o < 1024; o <<= 1) {
        int t = (threadIdx.x >= (unsigned)o) ? sh[threadIdx.x - o] : 0;
        __syncthreads();
        sh[threadIdx.x] += t;
        __syncthreads();
    }
    offs[i] = sh[threadIdx.x] - v;
    if (threadIdx.x == 1023) bsum[blockIdx.x] = sh[1023];
}

// 1 block, 64 threads: two independent 32-wide exclusive scans.
__global__ __launch_bounds__(64) void k_scanB64(const int* __restrict__ bsum, int* __restrict__ bbase) {
    __shared__ int sh[64];
    int t = threadIdx.x;
    int v = bsum[t];
    sh[t] = v;
    __syncthreads();
    for (int o = 1; o < 32; o <<= 1) {
        int a = ((t & 31) >= o) ? sh[t - o] : 0;
        __syncthreads();
        sh[t] += a;
        __syncthreads();
    }
    bbase[t] = sh[t] - v;
}

__global__ __launch_bounds__(1024) void k_scanC2(int* __restrict__ scnt, int* __restrict__ qcnt,
                                                 int* __restrict__ soffs, int* __restrict__ qoffs,
                                                 const int* __restrict__ bbase, int N, int M) {
    const int grp = blockIdx.x >> 5;
    const int blk = blockIdx.x & 31;
    int* cnt  = grp ? qcnt  : scnt;
    int* offs = grp ? qoffs : soffs;
    int i = blk * 1024 + threadIdx.x;
    int o = offs[i] + bbase[blockIdx.x];
    offs[i] = o;
    cnt[i]  = o;                         // cursor for scatter
    if (i == NC3 - 1) offs[NC3] = grp ? M : N;
}

// FROZEN preproc folded into source scatter (validated R5/R8/R9/R10).
__global__ void k_scatM(const float* __restrict__ sp, int N,
                        const float* __restrict__ tp, int M,
                        int* __restrict__ scur, float4* __restrict__ spts, int* __restrict__ sidx,
                        int* __restrict__ qcur, float4* __restrict__ qpts) {
    int i = blockIdx.x * 256 + threadIdx.x;
    if (i < N) {
        float x = sp[3 * i], y = sp[3 * i + 1], z = sp[3 * i + 2];
        int pos = atomicAdd(&scur[mkey3(mcell(x), mcell(y), mcell(z))], 1);
        float s2 = __fadd_rn(__fadd_rn(__fmul_rn(x, x), __fmul_rn(y, y)), __fmul_rn(z, z));
        spts[pos] = make_float4(-2.f * x, -2.f * y, -2.f * z, s2);
        sidx[pos] = i;
    } else if (i < N + M) {
        int j = i - N;
        float x = tp[3 * j], y = tp[3 * j + 1], z = tp[3 * j + 2];
        int pos = atomicAdd(&qcur[mkey3(mcell(x), mcell(y), mcell(z))], 1);
        qpts[pos] = make_float4(x, y, z, __int_as_float(j));
    }
}

// ---------------- Morton-ball kNN + interpolation ----------------
// Block = 64 Morton-adjacent queries (lane = query, all 16 waves alias them);
// waves chunk-split contiguous candidate spans (R7's validated hot loop).
// Round 0: smallest centroid octant (contiguous Morton span) with >=3 pts
// -> per-query b3 -> block rmax. Round 1: FRESH selection over all cells with
// boxdist(cell, bbox) <= rmax^2+SLACK (superset of every query's ball
// radius sqrt(b3+MARGIN) -> contains the frozen top-3; no duplicates since
// round-0 result is discarded). Scoring = FROZEN formula (R5); selection via
// u64 (score,idx) keys (R8-R10) -> order-independent, bit-exact.
#define SCORE_INS(pp, sj) do {                                                 \
    float _a = fmaf((pp).z, qz, fmaf((pp).y, qy, __fmul_rn((pp).x, qx)));      \
    float _d = __fadd_rn(__fadd_rn(t2, _a), (pp).w);                           \
    if (__any(_d <= d2f)) {                                                    \
        unsigned long long _k =                                                \
            ((unsigned long long)key_hi(_d) << 32) | (unsigned)(sj);           \
        insert3k(_k, k0, k1, k2);                                              \
        d2f = bound3(k2);                                                      \
    }                                                                          \
} while (0)

#define SCAN_SPAN(Sa, Sb) do {                                                 \
    int _len = (Sb) - (Sa);                                                    \
    if (_len > 0) {                                                            \
        int _ch = (_len + 15) >> 4;                                            \
        int _a = (Sa) + wave * _ch;                                            \
        int _b = min(_a + _ch, (Sb));                                          \
        int _p = _a;                                                           \
        for (; _p + 8 <= _b; _p += 8) {                                        \
            float4 s0 = spts[_p+0], s1 = spts[_p+1], s2v = spts[_p+2], s3 = spts[_p+3]; \
            float4 s4 = spts[_p+4], s5 = spts[_p+5], s6 = spts[_p+6], s7 = spts[_p+7]; \
            int j0 = sidx[_p+0], j1 = sidx[_p+1], j2 = sidx[_p+2], j3 = sidx[_p+3]; \
            int j4 = sidx[_p+4], j5 = sidx[_p+5], j6 = sidx[_p+6], j7 = sidx[_p+7]; \
            SCORE_INS(s0, j0); SCORE_INS(s1, j1); SCORE_INS(s2v, j2); SCORE_INS(s3, j3); \
            SCORE_INS(s4, j4); SCORE_INS(s5, j5); SCORE_INS(s6, j6); SCORE_INS(s7, j7); \
        }                                                                      \
        for (; _p < _b; ++_p) { float4 sv = spts[_p]; int jv = sidx[_p]; SCORE_INS(sv, jv); } \
    }                                                                          \
} while (0)

__device__ __forceinline__ float cellgap(int c, float blo, float bhi) {
    float clo = (c == 0)       ? -finf() : (BLO + (float)c * CS);
    float chi = (c == GD3 - 1) ?  finf() : (BLO + (float)(c + 1) * CS);
    return fmaxf(fmaxf(clo - bhi, blo - chi), 0.f);
}

__global__ __launch_bounds__(1024, 8) void k_knn_m(
        const float4* __restrict__ spts, const int* __restrict__ sidx,
        const int* __restrict__ soffs, const float4* __restrict__ qpts,
        const float* __restrict__ feat, float* __restrict__ out, int M, int C) {
    __shared__ uint2 s_k[16][3][64];
    __shared__ float s_w[3][64];
    __shared__ int   s_j[3][64];
    __shared__ int   s_o[64];
    __shared__ int   s_rng[6];
    __shared__ float s_rr;

    const int tid  = threadIdx.x;
    const int lane = tid & 63;
    const int wave = __builtin_amdgcn_readfirstlane(tid >> 6);

    const int qid = blockIdx.x * 64 + lane;
    const bool valid = qid < M;
    float4 qp = valid ? qpts[qid] : make_float4(0.f, 0.f, 0.f, __int_as_float(0));
    const float qx = qp.x, qy = qp.y, qz = qp.z;
    const int orig = __float_as_int(qp.w);
    const float t2 = __fadd_rn(__fadd_rn(__fmul_rn(qx, qx), __fmul_rn(qy, qy)),
                               __fmul_rn(qz, qz));   // FROZEN (R5)

    // block bbox over valid lanes (identical in every wave)
    float bx0 = valid ? qx : finf(), bx1 = valid ? qx : -finf();
    float by0 = valid ? qy : finf(), by1 = valid ? qy : -finf();
    float bz0 = valid ? qz : finf(), bz1 = valid ? qz : -finf();
    #pragma unroll
    for (int r = 1; r < 64; r <<= 1) {
        bx0 = fminf(bx0, __shfl_xor(bx0, r, 64)); bx1 = fmaxf(bx1, __shfl_xor(bx1, r, 64));
        by0 = fminf(by0, __shfl_xor(by0, r, 64)); by1 = fmaxf(by1, __shfl_xor(by1, r, 64));
        bz0 = fminf(bz0, __shfl_xor(bz0, r, 64)); bz1 = fmaxf(bz1, __shfl_xor(bz1, r, 64));
    }

    // ---- round 0: smallest centroid octant with >= 3 points ----
    const unsigned ck = mkey3(mcell(0.5f * (bx0 + bx1)),
                              mcell(0.5f * (by0 + by1)),
                              mcell(0.5f * (bz0 + bz1)));
    int S0 = 0, S1 = 0;
    #pragma unroll
    for (int L = 1; L <= 5; ++L) {
        unsigned sz = 1u << (3 * L);
        unsigned base = ck & ~(sz - 1u);
        int a = __builtin_amdgcn_readfirstlane(soffs[base]);
        int b = __builtin_amdgcn_readfirstlane(soffs[base + sz]);
        S0 = a; S1 = b;
        if (b - a >= 3) break;
    }

    unsigned long long k0 = ~0ULL, k1 = ~0ULL, k2 = ~0ULL;
    float d2f = finf();
    SCAN_SPAN(S0, S1);
    s_k[wave][0][lane] = make_uint2((unsigned)k0, (unsigned)(k0 >> 32));
    s_k[wave][1][lane] = make_uint2((unsigned)k1, (unsigned)(k1 >> 32));
    s_k[wave][2][lane] = make_uint2((unsigned)k2, (unsigned)(k2 >> 32));
    __syncthreads();

    if (wave == 0) {
        unsigned long long K0 = ~0ULL, K1 = ~0ULL, K2 = ~0ULL;
        #pragma unroll
        for (int w = 0; w < 16; ++w)
            #pragma unroll
            for (int r = 0; r < 3; ++r) {
                uint2 u = s_k[w][r][lane];
                insert3k(((unsigned long long)u.y << 32) | u.x, K0, K1, K2);
            }
        float rq2 = valid ? __fadd_rn(bound3(K2), MARGIN) : 0.f;
        #pragma unroll
        for (int r = 1; r < 64; r <<= 1) rq2 = fmaxf(rq2, __shfl_xor(rq2, r, 64));
        if (lane == 0) {
            float rmax = sqrtf(rq2) + RPAD;
            s_rr = rq2 + SLACK;
            s_rng[0] = mcell(bx0 - rmax); s_rng[1] = mcell(bx1 + rmax);
            s_rng[2] = mcell(by0 - rmax); s_rng[3] = mcell(by1 + rmax);
            s_rng[4] = mcell(bz0 - rmax); s_rng[5] = mcell(bz1 + rmax);
        }
    }
    __syncthreads();

    const float rr = s_rr;
    const int cxlo = s_rng[0], cxhi = s_rng[1];
    const int cylo = s_rng[2], cyhi = s_rng[3];
    const int czlo = s_rng[4], czhi = s_rng[5];

    // ---- round 1: fresh selection over all cells within rr of the bbox ----
    k0 = k1 = k2 = ~0ULL; d2f = finf();
    for (int cz = czlo; cz <= czhi; ++cz) {
        float gz = cellgap(cz, bz0, bz1);
        float gz2 = gz * gz;
        if (gz2 > rr) continue;
        for (int cy = cylo; cy <= cyhi; ++cy) {
            float gy = cellgap(cy, by0, by1);
            float gzy = gz2 + gy * gy;
            if (gzy > rr) continue;
            for (int cx = cxlo; cx <= cxhi; ++cx) {
                float gx = cellgap(cx, bx0, bx1);
                if (gzy + gx * gx > rr) continue;
                unsigned key = mkey3(cx, cy, cz);
                int a = __builtin_amdgcn_readfirstlane(soffs[key]);
                int b = __builtin_amdgcn_readfirstlane(soffs[key + 1]);
                SCAN_SPAN(a, b);
            }
        }
    }
    s_k[wave][0][lane] = make_uint2((unsigned)k0, (unsigned)(k0 >> 32));
    s_k[wave][1][lane] = make_uint2((unsigned)k1, (unsigned)(k1 >> 32));
    s_k[wave][2][lane] = make_uint2((unsigned)k2, (unsigned)(k2 >> 32));
    __syncthreads();

    if (wave == 0) {
        unsigned long long K0 = ~0ULL, K1 = ~0ULL, K2 = ~0ULL;
        #pragma unroll
        for (int w = 0; w < 16; ++w)
            #pragma unroll
            for (int r = 0; r < 3; ++r) {
                uint2 u = s_k[w][r][lane];
                insert3k(((unsigned long long)u.y << 32) | u.x, K0, K1, K2);
            }
        float b0 = key_d(K0), b1 = key_d(K1), b2 = key_d(K2);
        // FROZEN weights (R5): w = 1/(d+eps); w /= (w0+w1)+w2
        float w0 = __fdiv_rn(1.f, __fadd_rn(b0, EPS));
        float w1 = __fdiv_rn(1.f, __fadd_rn(b1, EPS));
        float w2 = __fdiv_rn(1.f, __fadd_rn(b2, EPS));
        float sum = __fadd_rn(__fadd_rn(w0, w1), w2);
        s_w[0][lane] = __fdiv_rn(w0, sum);
        s_w[1][lane] = __fdiv_rn(w1, sum);
        s_w[2][lane] = __fdiv_rn(w2, sum);
        s_j[0][lane] = (int)(unsigned)(K0 & 0xffffffffu);
        s_j[1][lane] = (int)(unsigned)(K1 & 0xffffffffu);
        s_j[2][lane] = (int)(unsigned)(K2 & 0xffffffffu);
        s_o[lane]    = orig;
    }
    __syncthreads();

    // interpolation: 16 threads/query, float4 loads/stores (C%64==0)
    const int tm = tid >> 4;
    const int qq = tid & 15;
    if (blockIdx.x * 64 + tm < M) {
        const int nv = C >> 6;
        const int row = s_o[tm];
        const float w0 = s_w[0][tm], w1 = s_w[1][tm], w2 = s_w[2][tm];
        const float4* f0 = (const float4*)(feat + (size_t)s_j[0][tm] * C) + qq * nv;
        const float4* f1 = (const float4*)(feat + (size_t)s_j[1][tm] * C) + qq * nv;
        const float4* f2 = (const float4*)(feat + (size_t)s_j[2][tm] * C) + qq * nv;
        float4* o = (float4*)(out + (size_t)row * C) + qq * nv;
        for (int r = 0; r < nv; ++r) {
            float4 a = f0[r], b = f1[r], c = f2[r];
            float4 v;
            v.x = w0 * a.x + w1 * b.x + w2 * c.x;
            v.y = w0 * a.y + w1 * b.y + w2 * c.y;
            v.z = w0 * a.z + w1 * b.z + w2 * c.z;
            v.w = w0 * a.w + w1 * b.w + w2 * c.w;
            o[r] = v;
        }
    }
}

// ---------------- dense fallback (validated R7 path) ----------------
#define NW 16
__global__ void knn_preproc(const float* __restrict__ sp, float4* __restrict__ sp4, int N) {
    int j = blockIdx.x * blockDim.x + threadIdx.x;
    if (j < N) {
        float x = sp[3 * j + 0], y = sp[3 * j + 1], z = sp[3 * j + 2];
        float s2 = __fadd_rn(__fadd_rn(__fmul_rn(x, x), __fmul_rn(y, y)), __fmul_rn(z, z));
        sp4[j] = make_float4(-2.f * x, -2.f * y, -2.f * z, s2);
    }
}
__device__ __forceinline__ void insert3_bl(float d, int j,
                                           float& d0, float& d1, float& d2,
                                           int& i0, int& i1, int& i2) {
    const bool c0 = d < d0, c1 = d < d1, c2 = d < d2;
    const float nd2 = c1 ? d1 : (c2 ? d : d2);
    const int   ni2 = c1 ? i1 : (c2 ? j : i2);
    const float nd1 = c0 ? d0 : (c1 ? d : d1);
    const int   ni1 = c0 ? i0 : (c1 ? j : i1);
    const float nd0 = c0 ? d : d0;
    const int   ni0 = c0 ? j : i0;
    d0 = nd0; d1 = nd1; d2 = nd2;
    i0 = ni0; i1 = ni1; i2 = ni2;
}
#define SCORE_INSERT(p, jv) do {                                          \
    float _a = fmaf((p).z, tz, fmaf((p).y, ty, __fmul_rn((p).x, tx)));    \
    float _d = __fadd_rn(__fadd_rn(t2, _a), (p).w);                       \
    if (__any(_d < d2))                                                   \
        insert3_bl(_d, (jv), d0, d1, d2, i0, i1, i2);                     \
} while (0)
__global__ __launch_bounds__(1024, 8) void knn_dense(
    const float4* __restrict__ sp4, const float* __restrict__ feat,
    const float* __restrict__ tp, float* __restrict__ out,
    int N, int M, int C) {
    __shared__ float s_d[NW][3][64];
    __shared__ int   s_i[NW][3][64];
    __shared__ float s_w[3][64];
    __shared__ int   s_j[3][64];
    const int tid  = threadIdx.x;
    const int lane = tid & 63;
    const int wave = __builtin_amdgcn_readfirstlane(tid >> 6);
    const int mbase = blockIdx.x * 64;
    const int m = mbase + lane;
    float tx = 0.f, ty = 0.f, tz = 0.f;
    if (m < M) { tx = tp[3 * m + 0]; ty = tp[3 * m + 1]; tz = tp[3 * m + 2]; }
    const float t2 = __fadd_rn(__fadd_rn(__fmul_rn(tx, tx), __fmul_rn(ty, ty)),
                               __fmul_rn(tz, tz));
    float d0 = FMAXV, d1 = FMAXV, d2 = FMAXV;
    int   i0 = 0,     i1 = 0,     i2 = 0;
    const int chunk = (N + NW - 1) / NW;
    const int jbeg = wave * chunk;
    const int jend = min(jbeg + chunk, N);
    int j = jbeg;
    for (; j + 8 <= jend; j += 8) {
        float4 p0 = sp4[j + 0], p1 = sp4[j + 1], p2 = sp4[j + 2], p3 = sp4[j + 3];
        float4 p4 = sp4[j + 4], p5 = sp4[j + 5], p6 = sp4[j + 6], p7 = sp4[j + 7];
        SCORE_INSERT(p0, j + 0); SCORE_INSERT(p1, j + 1);
        SCORE_INSERT(p2, j + 2); SCORE_INSERT(p3, j + 3);
        SCORE_INSERT(p4, j + 4); SCORE_INSERT(p5, j + 5);
        SCORE_INSERT(p6, j + 6); SCORE_INSERT(p7, j + 7);
    }
    for (; j < jend; ++j) { float4 p = sp4[j]; SCORE_INSERT(p, j); }
    s_d[wave][0][lane] = d0; s_d[wave][1][lane] = d1; s_d[wave][2][lane] = d2;
    s_i[wave][0][lane] = i0; s_i[wave][1][lane] = i1; s_i[wave][2][lane] = i2;
    __syncthreads();
    if (wave == 0) {
        float b0 = FMAXV, b1 = FMAXV, b2 = FMAXV;
        int   j0 = 0,     j1 = 0,     j2 = 0;
        #pragma unroll
        for (int w = 0; w < NW; ++w)
            #pragma unroll
            for (int k = 0; k < 3; ++k)
                insert3_bl(s_d[w][k][lane], s_i[w][k][lane], b0, b1, b2, j0, j1, j2);
        float w0 = __fdiv_rn(1.f, __fadd_rn(b0, EPS));
        float w1 = __fdiv_rn(1.f, __fadd_rn(b1, EPS));
        float w2 = __fdiv_rn(1.f, __fadd_rn(b2, EPS));
        float sum = __fadd_rn(__fadd_rn(w0, w1), w2);
        s_w[0][lane] = __fdiv_rn(w0, sum);
        s_w[1][lane] = __fdiv_rn(w1, sum);
        s_w[2][lane] = __fdiv_rn(w2, sum);
        s_j[0][lane] = j0; s_j[1][lane] = j1; s_j[2][lane] = j2;
    }
    __syncthreads();
    const int tm = tid >> 4;
    const int qq = tid & 15;
    const int gm = mbase + tm;
    if (gm < M) {
        const int nv = C >> 6;
        const float w0 = s_w[0][tm], w1 = s_w[1][tm], w2 = s_w[2][tm];
        const float4* f0 = (const float4*)(feat + (size_t)s_j[0][tm] * C) + qq * nv;
        const float4* f1 = (const float4*)(feat + (size_t)s_j[1][tm] * C) + qq * nv;
        const float4* f2 = (const float4*)(feat + (size_t)s_j[2][tm] * C) + qq * nv;
        float4* o = (float4*)(out + (size_t)gm * C) + qq * nv;
        for (int r = 0; r < nv; ++r) {
            float4 a = f0[r], b = f1[r], c = f2[r];
            float4 v;
            v.x = w0 * a.x + w1 * b.x + w2 * c.x;
            v.y = w0 * a.y + w1 * b.y + w2 * c.y;
            v.z = w0 * a.z + w1 * b.z + w2 * c.z;
            v.w = w0 * a.w + w1 * b.w + w2 * c.w;
            o[r] = v;
        }
    }
}

// ---------------- host ----------------
static inline size_t align256(size_t x) { return (x + 255) & ~(size_t)255; }

extern "C" void kernel_launch(void* const* d_in, const int* in_sizes, int n_in,
                              void* d_out, int out_size, void* d_ws, size_t ws_size,
                              hipStream_t stream) {
    const float* sp   = (const float*)d_in[0];  // source_points [N,3]
    const float* feat = (const float*)d_in[1];  // source_features [N,C]
    const float* tp   = (const float*)d_in[2];  // target_points [M,3]
    float* out = (float*)d_out;                 // [M,C] fp32

    const int N = in_sizes[0] / 3;
    const int C = in_sizes[1] / N;
    const int M = in_sizes[2] / 3;

    // ws layout (Morton path)
    size_t oScnt  = 0;                                       // NC3 ints
    size_t oQcnt  = oScnt + (size_t)NC3 * 4;                 // NC3 ints (adjacent -> one memset)
    size_t oSoffs = align256(oQcnt + (size_t)NC3 * 4);       // NC3+1 ints
    size_t oQoffs = align256(oSoffs + (size_t)(NC3 + 1) * 4);
    size_t oBsum  = align256(oQoffs + (size_t)(NC3 + 1) * 4); // 64 ints
    size_t oBbase = align256(oBsum + 64 * 4);                 // 64 ints
    size_t oSpts  = align256(oBbase + 64 * 4);                // N float4
    size_t oSidx  = align256(oSpts + (size_t)N * 16);         // N ints
    size_t oQpts  = align256(oSidx + (size_t)N * 4);          // M float4
    size_t need   = oQpts + (size_t)M * 16;

    if (ws_size >= need && (C & 63) == 0) {
        char* ws = (char*)d_ws;
        int*    scnt  = (int*)(ws + oScnt);
        int*    qcnt  = (int*)(ws + oQcnt);
        int*    soffs = (int*)(ws + oSoffs);
        int*    qoffs = (int*)(ws + oQoffs);
        int*    bsum  = (int*)(ws + oBsum);
        int*    bbase = (int*)(ws + oBbase);
        float4* spts  = (float4*)(ws + oSpts);
        int*    sidxp = (int*)(ws + oSidx);
        float4* qpts  = (float4*)(ws + oQpts);

        hipMemsetAsync(scnt, 0, (size_t)2 * NC3 * 4, stream);
        int nmBlocks = (N + M + 255) / 256;
        k_histM<<<nmBlocks, 256, 0, stream>>>(sp, N, tp, M, scnt, qcnt);
        k_scanA2<<<64, 1024, 0, stream>>>(scnt, qcnt, soffs, qoffs, bsum);
        k_scanB64<<<1, 64, 0, stream>>>(bsum, bbase);
        k_scanC2<<<64, 1024, 0, stream>>>(scnt, qcnt, soffs, qoffs, bbase, N, M);
        k_scatM<<<nmBlocks, 256, 0, stream>>>(sp, N, tp, M, scnt, spts, sidxp, qcnt, qpts);
        k_knn_m<<<(M + 63) / 64, 1024, 0, stream>>>(spts, sidxp, soffs, qpts, feat, out, M, C);
    } else {
        // dense fallback (validated R7)
        float4* sp4 = (float4*)d_ws;
        knn_preproc<<<(N + 255) / 256, 256, 0, stream>>>(sp, sp4, N);
        knn_dense<<<(M + 63) / 64, 1024, 0, stream>>>(sp4, feat, tp, out, N, M, C);
    }
}

// Round 12
// 157.991 us; speedup vs baseline: 69.6436x; 69.6436x over previous
//
#include <hip/hip_runtime.h>
#include <math.h>
#include <stdint.h>

#define EPS 1e-8f
#define FMAXV 3.402823466e38f

// ---------------- 1-D x-bucket parameters ----------------
#define NB 1024
#define BLO (-6.0f)
#define INVBW (85.333336f)      // 1024/12; only monotone consistency needed
#define MARGIN 2e-4f            // >> max |frozen score - true dist^2| (~4e-5)

__device__ __forceinline__ int cell1d(float x) {
    int c = (int)floorf((x - BLO) * INVBW);
    return min(max(c, 0), NB - 1);
}
__device__ __forceinline__ float finf() { return __uint_as_float(0x7f800000u); }

// Monotone float->uint key; (key_hi(d)<<32)|idx = lexicographic (d, idx)
// == jax.lax.top_k lowest-index tie-break (validated R8-R11).
__device__ __forceinline__ unsigned key_hi(float d) {
    unsigned b = __float_as_uint(d);
    return (b & 0x80000000u) ? ~b : (b | 0x80000000u);
}
__device__ __forceinline__ float key_d(unsigned long long k) {
    unsigned h = (unsigned)(k >> 32);
    unsigned b = (h & 0x80000000u) ? (h & 0x7fffffffu) : ~h;
    return __uint_as_float(b);
}
__device__ __forceinline__ unsigned long long shfl_xor_u64(unsigned long long v, int m) {
    int lo = __shfl_xor((int)(unsigned)(v & 0xffffffffu), m, 64);
    int hi = __shfl_xor((int)(unsigned)(v >> 32), m, 64);
    return ((unsigned long long)(unsigned)hi << 32) | (unsigned)lo;
}
// Branchless sorted top-3 insert on u64 keys (strict '<' lexicographic).
__device__ __forceinline__ void insert3k(unsigned long long k,
        unsigned long long& k0, unsigned long long& k1, unsigned long long& k2) {
    const bool c0 = k < k0, c1 = k < k1, c2 = k < k2;
    k2 = c1 ? k1 : (c2 ? k : k2);
    k1 = c0 ? k0 : (c1 ? k : k1);
    k0 = c0 ? k : k0;
}
// Branchless top-3 insert, values only (for the phase-0 bound).
__device__ __forceinline__ void insert3f(float d, float& d0, float& d1, float& d2) {
    const bool c0 = d < d0, c1 = d < d1, c2 = d < d2;
    d2 = c1 ? d1 : (c2 ? d : d2);
    d1 = c0 ? d0 : (c1 ? d : d1);
    d0 = c0 ? d : d0;
}

// ---------------- build: histogram / scan / scatter (R9-validated) --------
__global__ void k_hist(const float* __restrict__ sp, int N, int* __restrict__ scnt) {
    int i = blockIdx.x * 256 + threadIdx.x;
    if (i < N) atomicAdd(&scnt[cell1d(sp[3 * i])], 1);
}

__global__ __launch_bounds__(1024) void k_scan1(int* __restrict__ scnt,
                                                int* __restrict__ soffs, int N) {
    __shared__ int sh[NB];
    int v = scnt[threadIdx.x];
    sh[threadIdx.x] = v;
    __syncthreads();
    for (int o = 1; o < NB; o <<= 1) {
        int t = (threadIdx.x >= (unsigned)o) ? sh[threadIdx.x - o] : 0;
        __syncthreads();
        sh[threadIdx.x] += t;
        __syncthreads();
    }
    int excl = sh[threadIdx.x] - v;
    scnt[threadIdx.x]  = excl;   // cursor for scatter
    soffs[threadIdx.x] = excl;
    if (threadIdx.x == NB - 1) soffs[NB] = N;
}

// FROZEN preproc folded into scatter (validated R5/R8-R11):
// spts[pos] = (-2x,-2y,-2z, s2), s2 = (x*x + y*y) + z*z strict no-FMA.
__global__ void k_scat(const float* __restrict__ sp, int N, int* __restrict__ scur,
                       float4* __restrict__ spts, int* __restrict__ sidx) {
    int i = blockIdx.x * 256 + threadIdx.x;
    if (i >= N) return;
    float x = sp[3 * i], y = sp[3 * i + 1], z = sp[3 * i + 2];
    int pos = atomicAdd(&scur[cell1d(x)], 1);
    float s2 = __fadd_rn(__fadd_rn(__fmul_rn(x, x), __fmul_rn(y, y)), __fmul_rn(z, z));
    spts[pos] = make_float4(-2.f * x, -2.f * y, -2.f * z, s2);
    sidx[pos] = i;
}

// ---------------- wave-per-query windowed kNN + interpolation ----------------
// One wave per query (qid wave-uniform -> scalar tp/soffs loads). Phase 0:
// 256 index-contiguous candidates centered at the query's bucket, lane-strided,
// values-only top-3 + butterfly-min -> b3 (true 3rd-best frozen score of that
// subset, an upper bound on the final 3rd-best). Phase 1: window halfwidth
// w = sqrt(b3+MARGIN) -> bucket range -> FRESH lane-strided scan with u64
// (score,idx) keys + one butterfly merge. Coverage: phase-0 top-3 lie inside
// the window (true d <= sqrt(b3+4e-5) < w); excluded points have frozen score
// > b3 + MARGIN - 4e-5 > b3 >= final 3rd-best. Scoring = FROZEN formula (R5);
// selection = u64 keys (R8-R11) -> order-independent, bit-exact.
#define SCORE_ONLY(pp) ({                                                     \
    float _a = fmaf((pp).z, qz, fmaf((pp).y, qy, __fmul_rn((pp).x, qx)));     \
    __fadd_rn(__fadd_rn(t2, _a), (pp).w); })

__global__ __launch_bounds__(256) void k_knn_w(
        const float4* __restrict__ spts, const int* __restrict__ sidx,
        const int* __restrict__ soffs, const float* __restrict__ tp,
        const float* __restrict__ feat, float* __restrict__ out,
        int N, int M, int C) {
    const int lane = threadIdx.x & 63;
    const int wave = __builtin_amdgcn_readfirstlane(threadIdx.x >> 6);
    const int qid  = blockIdx.x * 4 + wave;          // wave-uniform
    if (qid >= M) return;                            // uniform branch

    const float qx = tp[3 * qid], qy = tp[3 * qid + 1], qz = tp[3 * qid + 2];
    const float t2 = __fadd_rn(__fadd_rn(__fmul_rn(qx, qx), __fmul_rn(qy, qy)),
                               __fmul_rn(qz, qz));   // FROZEN (R5)

    // ---- phase 0: 256 candidates centered on the query's bucket ----
    const int c  = cell1d(qx);
    const int ca = soffs[c], cb = soffs[c + 1];      // scalar loads
    const int ctr = (ca + cb) >> 1;
    const int p0 = min(max(ctr - 128, 0), max(N - 256, 0));
    const int p1 = min(p0 + 256, N);

    float d0 = FMAXV, d1 = FMAXV, d2 = FMAXV;
    for (int p = p0 + lane; p < p1; p += 64) {
        float4 pt = spts[p];
        insert3f(SCORE_ONLY(pt), d0, d1, d2);
    }
    #pragma unroll
    for (int r = 1; r < 64; r <<= 1) {
        float e0 = __shfl_xor(d0, r, 64);
        float e1 = __shfl_xor(d1, r, 64);
        float e2 = __shfl_xor(d2, r, 64);
        insert3f(e0, d0, d1, d2);
        insert3f(e1, d0, d1, d2);
        insert3f(e2, d0, d1, d2);
    }
    const float w = sqrtf(__fadd_rn(d2, MARGIN));

    // ---- phase 1: fresh u64-key scan of the full window ----
    const int blo = cell1d(qx - w), bhi = cell1d(qx + w);
    const int S0 = soffs[blo], S1 = soffs[bhi + 1];  // scalar loads

    unsigned long long k0 = ~0ULL, k1 = ~0ULL, k2 = ~0ULL;
    int p = S0 + lane;
    for (; p + 64 < S1; p += 128) {
        float4 ptA = spts[p];      int jA = sidx[p];
        float4 ptB = spts[p + 64]; int jB = sidx[p + 64];
        float dA = SCORE_ONLY(ptA);
        float dB = SCORE_ONLY(ptB);
        insert3k(((unsigned long long)key_hi(dA) << 32) | (unsigned)jA, k0, k1, k2);
        insert3k(((unsigned long long)key_hi(dB) << 32) | (unsigned)jB, k0, k1, k2);
    }
    if (p < S1) {
        float4 ptA = spts[p]; int jA = sidx[p];
        float dA = SCORE_ONLY(ptA);
        insert3k(((unsigned long long)key_hi(dA) << 32) | (unsigned)jA, k0, k1, k2);
    }
    // butterfly merge of 64 disjoint partial top-3 sets -> identical in all lanes
    #pragma unroll
    for (int r = 1; r < 64; r <<= 1) {
        unsigned long long m0 = shfl_xor_u64(k0, r);
        unsigned long long m1 = shfl_xor_u64(k1, r);
        unsigned long long m2 = shfl_xor_u64(k2, r);
        insert3k(m0, k0, k1, k2);
        insert3k(m1, k0, k1, k2);
        insert3k(m2, k0, k1, k2);
    }

    // FROZEN weights (R5): w = 1/(d+eps); w /= (w0+w1)+w2  (all lanes, redundant)
    const float b0 = key_d(k0), b1 = key_d(k1), b2 = key_d(k2);
    const float w0r = __fdiv_rn(1.f, __fadd_rn(b0, EPS));
    const float w1r = __fdiv_rn(1.f, __fadd_rn(b1, EPS));
    const float w2r = __fdiv_rn(1.f, __fadd_rn(b2, EPS));
    const float sum = __fadd_rn(__fadd_rn(w0r, w1r), w2r);
    const float w0 = __fdiv_rn(w0r, sum);
    const float w1 = __fdiv_rn(w1r, sum);
    const float w2 = __fdiv_rn(w2r, sum);
    const int j0 = (int)(unsigned)(k0 & 0xffffffffu);
    const int j1 = (int)(unsigned)(k1 & 0xffffffffu);
    const int j2 = (int)(unsigned)(k2 & 0xffffffffu);

    // interpolation: whole wave on this query's row, float2 per lane (C even)
    const float2* f0 = (const float2*)(feat + (size_t)j0 * C);
    const float2* f1 = (const float2*)(feat + (size_t)j1 * C);
    const float2* f2 = (const float2*)(feat + (size_t)j2 * C);
    float2* o = (float2*)(out + (size_t)qid * C);
    const int nc2 = C >> 1;
    for (int cc = lane; cc < nc2; cc += 64) {
        float2 a = f0[cc], b = f1[cc], d = f2[cc];
        o[cc] = make_float2(w0 * a.x + w1 * b.x + w2 * d.x,
                            w0 * a.y + w1 * b.y + w2 * d.y);
    }
}

// ---------------- dense fallback (validated R7 path) ----------------
#define NW 16
__global__ void knn_preproc(const float* __restrict__ sp, float4* __restrict__ sp4, int N) {
    int j = blockIdx.x * blockDim.x + threadIdx.x;
    if (j < N) {
        float x = sp[3 * j + 0], y = sp[3 * j + 1], z = sp[3 * j + 2];
        float s2 = __fadd_rn(__fadd_rn(__fmul_rn(x, x), __fmul_rn(y, y)), __fmul_rn(z, z));
        sp4[j] = make_float4(-2.f * x, -2.f * y, -2.f * z, s2);
    }
}
__device__ __forceinline__ void insert3_bl(float d, int j,
                                           float& d0, float& d1, float& d2,
                                           int& i0, int& i1, int& i2) {
    const bool c0 = d < d0, c1 = d < d1, c2 = d < d2;
    const float nd2 = c1 ? d1 : (c2 ? d : d2);
    const int   ni2 = c1 ? i1 : (c2 ? j : i2);
    const float nd1 = c0 ? d0 : (c1 ? d : d1);
    const int   ni1 = c0 ? i0 : (c1 ? j : i1);
    const float nd0 = c0 ? d : d0;
    const int   ni0 = c0 ? j : i0;
    d0 = nd0; d1 = nd1; d2 = nd2;
    i0 = ni0; i1 = ni1; i2 = ni2;
}
#define SCORE_INSERT(p, jv) do {                                          \
    float _a = fmaf((p).z, tz, fmaf((p).y, ty, __fmul_rn((p).x, tx)));    \
    float _d = __fadd_rn(__fadd_rn(t2, _a), (p).w);                       \
    if (__any(_d < d2))                                                   \
        insert3_bl(_d, (jv), d0, d1, d2, i0, i1, i2);                     \
} while (0)
__global__ __launch_bounds__(1024, 8) void knn_dense(
    const float4* __restrict__ sp4, const float* __restrict__ feat,
    const float* __restrict__ tp, float* __restrict__ out,
    int N, int M, int C) {
    __shared__ float s_d[NW][3][64];
    __shared__ int   s_i[NW][3][64];
    __shared__ float s_w[3][64];
    __shared__ int   s_j[3][64];
    const int tid  = threadIdx.x;
    const int lane = tid & 63;
    const int wave = __builtin_amdgcn_readfirstlane(tid >> 6);
    const int mbase = blockIdx.x * 64;
    const int m = mbase + lane;
    float tx = 0.f, ty = 0.f, tz = 0.f;
    if (m < M) { tx = tp[3 * m + 0]; ty = tp[3 * m + 1]; tz = tp[3 * m + 2]; }
    const float t2 = __fadd_rn(__fadd_rn(__fmul_rn(tx, tx), __fmul_rn(ty, ty)),
                               __fmul_rn(tz, tz));
    float d0 = FMAXV, d1 = FMAXV, d2 = FMAXV;
    int   i0 = 0,     i1 = 0,     i2 = 0;
    const int chunk = (N + NW - 1) / NW;
    const int jbeg = wave * chunk;
    const int jend = min(jbeg + chunk, N);
    int j = jbeg;
    for (; j + 8 <= jend; j += 8) {
        float4 p0 = sp4[j + 0], p1 = sp4[j + 1], p2 = sp4[j + 2], p3 = sp4[j + 3];
        float4 p4 = sp4[j + 4], p5 = sp4[j + 5], p6 = sp4[j + 6], p7 = sp4[j + 7];
        SCORE_INSERT(p0, j + 0); SCORE_INSERT(p1, j + 1);
        SCORE_INSERT(p2, j + 2); SCORE_INSERT(p3, j + 3);
        SCORE_INSERT(p4, j + 4); SCORE_INSERT(p5, j + 5);
        SCORE_INSERT(p6, j + 6); SCORE_INSERT(p7, j + 7);
    }
    for (; j < jend; ++j) { float4 p = sp4[j]; SCORE_INSERT(p, j); }
    s_d[wave][0][lane] = d0; s_d[wave][1][lane] = d1; s_d[wave][2][lane] = d2;
    s_i[wave][0][lane] = i0; s_i[wave][1][lane] = i1; s_i[wave][2][lane] = i2;
    __syncthreads();
    if (wave == 0) {
        float b0 = FMAXV, b1 = FMAXV, b2 = FMAXV;
        int   j0 = 0,     j1 = 0,     j2 = 0;
        #pragma unroll
        for (int w = 0; w < NW; ++w)
            #pragma unroll
            for (int k = 0; k < 3; ++k)
                insert3_bl(s_d[w][k][lane], s_i[w][k][lane], b0, b1, b2, j0, j1, j2);
        float w0 = __fdiv_rn(1.f, __fadd_rn(b0, EPS));
        float w1 = __fdiv_rn(1.f, __fadd_rn(b1, EPS));
        float w2 = __fdiv_rn(1.f, __fadd_rn(b2, EPS));
        float sum = __fadd_rn(__fadd_rn(w0, w1), w2);
        s_w[0][lane] = __fdiv_rn(w0, sum);
        s_w[1][lane] = __fdiv_rn(w1, sum);
        s_w[2][lane] = __fdiv_rn(w2, sum);
        s_j[0][lane] = j0; s_j[1][lane] = j1; s_j[2][lane] = j2;
    }
    __syncthreads();
    const int tm = tid >> 4;
    const int qq = tid & 15;
    const int gm = mbase + tm;
    if (gm < M) {
        const int nv = C >> 6;
        const float w0 = s_w[0][tm], w1 = s_w[1][tm], w2 = s_w[2][tm];
        const float4* f0 = (const float4*)(feat + (size_t)s_j[0][tm] * C) + qq * nv;
        const float4* f1 = (const float4*)(feat + (size_t)s_j[1][tm] * C) + qq * nv;
        const float4* f2 = (const float4*)(feat + (size_t)s_j[2][tm] * C) + qq * nv;
        float4* o = (float4*)(out + (size_t)gm * C) + qq * nv;
        for (int r = 0; r < nv; ++r) {
            float4 a = f0[r], b = f1[r], c = f2[r];
            float4 v;
            v.x = w0 * a.x + w1 * b.x + w2 * c.x;
            v.y = w0 * a.y + w1 * b.y + w2 * c.y;
            v.z = w0 * a.z + w1 * b.z + w2 * c.z;
            v.w = w0 * a.w + w1 * b.w + w2 * c.w;
            o[r] = v;
        }
    }
}

// ---------------- host ----------------
static inline size_t align256(size_t x) { return (x + 255) & ~(size_t)255; }

extern "C" void kernel_launch(void* const* d_in, const int* in_sizes, int n_in,
                              void* d_out, int out_size, void* d_ws, size_t ws_size,
                              hipStream_t stream) {
    const float* sp   = (const float*)d_in[0];  // source_points [N,3]
    const float* feat = (const float*)d_in[1];  // source_features [N,C]
    const float* tp   = (const float*)d_in[2];  // target_points [M,3]
    float* out = (float*)d_out;                 // [M,C] fp32

    const int N = in_sizes[0] / 3;
    const int C = in_sizes[1] / N;
    const int M = in_sizes[2] / 3;

    // ws layout (windowed wave-per-query path)
    size_t oScnt  = 0;                                       // NB ints (then cursor)
    size_t oSoffs = align256(oScnt + (size_t)NB * 4);        // NB+1 ints
    size_t oSpts  = align256(oSoffs + (size_t)(NB + 1) * 4); // N float4
    size_t oSidx  = align256(oSpts + (size_t)N * 16);        // N ints
    size_t need   = oSidx + (size_t)N * 4;

    if (ws_size >= need && (C & 1) == 0 && N >= 256) {
        char* ws = (char*)d_ws;
        int*    scnt  = (int*)(ws + oScnt);
        int*    soffs = (int*)(ws + oSoffs);
        float4* spts  = (float4*)(ws + oSpts);
        int*    sidxp = (int*)(ws + oSidx);

        hipMemsetAsync(scnt, 0, (size_t)NB * 4, stream);
        k_hist<<<(N + 255) / 256, 256, 0, stream>>>(sp, N, scnt);
        k_scan1<<<1, NB, 0, stream>>>(scnt, soffs, N);
        k_scat<<<(N + 255) / 256, 256, 0, stream>>>(sp, N, scnt, spts, sidxp);
        k_knn_w<<<(M + 3) / 4, 256, 0, stream>>>(spts, sidxp, soffs, tp, feat, out, N, M, C);
    } else {
        // dense fallback (validated R7)
        float4* sp4 = (float4*)d_ws;
        knn_preproc<<<(N + 255) / 256, 256, 0, stream>>>(sp, sp4, N);
        knn_dense<<<(M + 63) / 64, 1024, 0, stream>>>(sp4, feat, tp, out, N, M, C);
    }
}

// Round 13
// 96.141 us; speedup vs baseline: 114.4470x; 1.6433x over previous
//
#include <hip/hip_runtime.h>
#include <math.h>
#include <stdint.h>

#define EPS 1e-8f
#define FMAXV 3.402823466e38f

// ---------------- 2-D (y,x) cell parameters ----------------
#define GD2 64
#define NC2 (GD2 * GD2)          // 4096 cells
#define BLO (-6.0f)
#define INVCS (5.3333335f)       // 64/12; only monotone consistency needed
#define MARGIN 2e-4f             // >> max |frozen score - true dist^2| (~4e-5)

__device__ __forceinline__ int mcell(float v) {
    int c = (int)floorf((v - BLO) * INVCS);
    return min(max(c, 0), GD2 - 1);
}
// source key: row-major, x minor -> per-row x-ranges are contiguous spans
__device__ __forceinline__ int skey2(float x, float y) {
    return mcell(y) * GD2 + mcell(x);
}
// query key: serpentine x within y-rows (locality only; any order is correct)
__device__ __forceinline__ int qkey2(float x, float y) {
    int r = mcell(y), c = mcell(x);
    return r * GD2 + ((r & 1) ? (GD2 - 1 - c) : c);
}
__device__ __forceinline__ float finf() { return __uint_as_float(0x7f800000u); }

// Monotone float->uint key; (key_hi(d)<<32)|idx = lexicographic (d, idx)
// == jax.lax.top_k lowest-index tie-break (validated R8-R12).
__device__ __forceinline__ unsigned key_hi(float d) {
    unsigned b = __float_as_uint(d);
    return (b & 0x80000000u) ? ~b : (b | 0x80000000u);
}
__device__ __forceinline__ float key_d(unsigned long long k) {
    unsigned h = (unsigned)(k >> 32);
    unsigned b = (h & 0x80000000u) ? (h & 0x7fffffffu) : ~h;
    return __uint_as_float(b);
}
__device__ __forceinline__ unsigned long long shfl_xor_u64(unsigned long long v, int m) {
    int lo = __shfl_xor((int)(unsigned)(v & 0xffffffffu), m, 64);
    int hi = __shfl_xor((int)(unsigned)(v >> 32), m, 64);
    return ((unsigned long long)(unsigned)hi << 32) | (unsigned)lo;
}
// Branchless sorted top-3 insert on u64 keys (strict '<' lexicographic).
__device__ __forceinline__ void insert3k(unsigned long long k,
        unsigned long long& k0, unsigned long long& k1, unsigned long long& k2) {
    const bool c0 = k < k0, c1 = k < k1, c2 = k < k2;
    k2 = c1 ? k1 : (c2 ? k : k2);
    k1 = c0 ? k0 : (c1 ? k : k1);
    k0 = c0 ? k : k0;
}
// Values-only sorted top-3 insert (phase-0 bound).
__device__ __forceinline__ void insert3f(float d, float& d0, float& d1, float& d2) {
    const bool c0 = d < d0, c1 = d < d1, c2 = d < d2;
    d2 = c1 ? d1 : (c2 ? d : d2);
    d1 = c0 ? d0 : (c1 ? d : d1);
    d0 = c0 ? d : d0;
}
// Sorted (3,3)->top-3 merge via order statistics (both inputs sorted asc):
//   r0 = min(a0,b0); r1 = min(a1,b1,max(a0,b0));
//   r2 = min(a2,b2,max(a1,b0),max(a0,b1))
__device__ __forceinline__ void merge3f(float b0, float b1, float b2,
                                        float& a0, float& a1, float& a2) {
    float r0 = fminf(a0, b0);
    float r1 = fminf(fminf(a1, b1), fmaxf(a0, b0));
    float r2 = fminf(fminf(a2, b2), fminf(fmaxf(a1, b0), fmaxf(a0, b1)));
    a0 = r0; a1 = r1; a2 = r2;
}
__device__ __forceinline__ unsigned long long umin64(unsigned long long a, unsigned long long b) { return a < b ? a : b; }
__device__ __forceinline__ unsigned long long umax64(unsigned long long a, unsigned long long b) { return a < b ? b : a; }
__device__ __forceinline__ void merge3k(unsigned long long b0, unsigned long long b1, unsigned long long b2,
        unsigned long long& a0, unsigned long long& a1, unsigned long long& a2) {
    unsigned long long r0 = umin64(a0, b0);
    unsigned long long r1 = umin64(umin64(a1, b1), umax64(a0, b0));
    unsigned long long r2 = umin64(umin64(a2, b2), umin64(umax64(a1, b0), umax64(a0, b1)));
    a0 = r0; a1 = r1; a2 = r2;
}

// ---------------- build: histogram / scan / scatter ----------------
__global__ void k_hist2D(const float* __restrict__ sp, int N,
                         const float* __restrict__ tp, int M,
                         int* __restrict__ scnt, int* __restrict__ qcnt) {
    int i = blockIdx.x * 256 + threadIdx.x;
    if (i < N) {
        atomicAdd(&scnt[skey2(sp[3 * i], sp[3 * i + 1])], 1);
    } else if (i < N + M) {
        int j = i - N;
        atomicAdd(&qcnt[qkey2(tp[3 * j], tp[3 * j + 1])], 1);
    }
}

// 2 blocks: 0 -> sources, 1 -> queries. 1024 threads x 4 cells each.
// cnt becomes the scatter cursor (exclusive offsets).
__global__ __launch_bounds__(1024) void k_scan4k(int* __restrict__ scnt, int* __restrict__ qcnt,
                                                 int* __restrict__ soffs, int* __restrict__ qoffs) {
    int* cnt  = blockIdx.x ? qcnt : scnt;
    int* offs = blockIdx.x ? qoffs : soffs;
    __shared__ int sh[1024];
    const int t = threadIdx.x;
    int4 v = ((const int4*)cnt)[t];
    int s = v.x + v.y + v.z + v.w;
    sh[t] = s;
    __syncthreads();
    for (int o = 1; o < 1024; o <<= 1) {
        int u = (t >= o) ? sh[t - o] : 0;
        __syncthreads();
        sh[t] += u;
        __syncthreads();
    }
    int base = sh[t] - s;
    int4 e = make_int4(base, base + v.x, base + v.x + v.y, base + v.x + v.y + v.z);
    ((int4*)offs)[t] = e;
    ((int4*)cnt)[t]  = e;   // cursor
    if (t == 1023) offs[NC2] = base + s;
}

// FROZEN preproc folded into source scatter (validated R5/R8-R12):
// spts[pos] = (-2x,-2y,-2z, s2), s2 = (x*x + y*y) + z*z strict no-FMA.
__global__ void k_scat2D(const float* __restrict__ sp, int N,
                         const float* __restrict__ tp, int M,
                         int* __restrict__ scur, float4* __restrict__ spts, int* __restrict__ sidx,
                         int* __restrict__ qcur, float4* __restrict__ qpts) {
    int i = blockIdx.x * 256 + threadIdx.x;
    if (i < N) {
        float x = sp[3 * i], y = sp[3 * i + 1], z = sp[3 * i + 2];
        int pos = atomicAdd(&scur[skey2(x, y)], 1);
        float s2 = __fadd_rn(__fadd_rn(__fmul_rn(x, x), __fmul_rn(y, y)), __fmul_rn(z, z));
        spts[pos] = make_float4(-2.f * x, -2.f * y, -2.f * z, s2);
        sidx[pos] = i;
    } else if (i < N + M) {
        int j = i - N;
        float x = tp[3 * j], y = tp[3 * j + 1], z = tp[3 * j + 2];
        int pos = atomicAdd(&qcur[qkey2(x, y)], 1);
        qpts[pos] = make_float4(x, y, z, __int_as_float(j));
    }
}

// ---------------- wave-per-query 2-D windowed kNN + interpolation ----------
// One wave per (sorted) query. Phase 0: 256 index-contiguous candidates
// centered on the query's cell ((y,x)-local -> near-true b3), values-only
// top-3 + sorted-merge butterfly. Phase 1: w = sqrt(b3+MARGIN); rows
// [cell(qy-w), cell(qy+w)], per row the contiguous span cols
// [cell(qx-w), cell(qx+w)]; FRESH lane-strided u64 (score,idx) scan + one
// sorted-merge butterfly. Coverage: phase-0 top-3 lie inside the window
// (true d <= sqrt(b3+4e-5) < w, mcell monotone); excluded points have frozen
// score > b3 + MARGIN - 4e-5 > b3 >= final 3rd-best. Scoring = FROZEN formula
// (R5); selection = u64 keys (R8-R12) -> order-independent, bit-exact.
#define SCORE_ONLY(pp) ({                                                     \
    float _a = fmaf((pp).z, qz, fmaf((pp).y, qy, __fmul_rn((pp).x, qx)));     \
    __fadd_rn(__fadd_rn(t2, _a), (pp).w); })

__global__ __launch_bounds__(256) void k_knn_w2(
        const float4* __restrict__ spts, const int* __restrict__ sidx,
        const int* __restrict__ soffs, const float4* __restrict__ qpts,
        const float* __restrict__ feat, float* __restrict__ out,
        int N, int M, int C) {
    const int lane = threadIdx.x & 63;
    const int wave = __builtin_amdgcn_readfirstlane(threadIdx.x >> 6);
    const int qid  = blockIdx.x * 4 + wave;          // wave-uniform
    if (qid >= M) return;                            // uniform branch

    float4 qp = qpts[qid];
    const float qx = qp.x, qy = qp.y, qz = qp.z;
    const int orig = __float_as_int(qp.w);
    const float t2 = __fadd_rn(__fadd_rn(__fmul_rn(qx, qx), __fmul_rn(qy, qy)),
                               __fmul_rn(qz, qz));   // FROZEN (R5)

    // ---- phase 0: 256 candidates centered on the query's (y,x) cell ----
    const int ck = mcell(qy) * GD2 + mcell(qx);
    const int ca = soffs[ck], cb = soffs[ck + 1];
    const int ctr = (ca + cb) >> 1;
    const int p0 = min(max(ctr - 128, 0), N - 256);

    float d0 = FMAXV, d1 = FMAXV, d2 = FMAXV;
    #pragma unroll
    for (int s = 0; s < 4; ++s) {
        float4 pt = spts[p0 + lane + s * 64];
        insert3f(SCORE_ONLY(pt), d0, d1, d2);
    }
    #pragma unroll
    for (int r = 1; r < 64; r <<= 1) {
        float e0 = __shfl_xor(d0, r, 64);
        float e1 = __shfl_xor(d1, r, 64);
        float e2 = __shfl_xor(d2, r, 64);
        merge3f(e0, e1, e2, d0, d1, d2);
    }
    const float w = sqrtf(__fadd_rn(d2, MARGIN));

    // ---- phase 1: fresh u64-key scan over the 2-D window ----
    const int rlo = mcell(qy - w), rhi = mcell(qy + w);
    const int clo = mcell(qx - w), chi = mcell(qx + w);

    unsigned long long k0 = ~0ULL, k1 = ~0ULL, k2 = ~0ULL;
    for (int r = rlo; r <= rhi; ++r) {
        const int b = r << 6;
        const int S0 = soffs[b + clo], S1 = soffs[b + chi + 1];
        for (int p = S0 + lane; p < S1; p += 64) {
            float4 pt = spts[p];
            int    j  = sidx[p];
            float  d  = SCORE_ONLY(pt);
            insert3k(((unsigned long long)key_hi(d) << 32) | (unsigned)j, k0, k1, k2);
        }
    }
    #pragma unroll
    for (int r = 1; r < 64; r <<= 1) {
        unsigned long long m0 = shfl_xor_u64(k0, r);
        unsigned long long m1 = shfl_xor_u64(k1, r);
        unsigned long long m2 = shfl_xor_u64(k2, r);
        merge3k(m0, m1, m2, k0, k1, k2);
    }

    // FROZEN weights (R5): w = 1/(d+eps); w /= (w0+w1)+w2  (all lanes, redundant)
    const float b0 = key_d(k0), b1 = key_d(k1), b2 = key_d(k2);
    const float w0r = __fdiv_rn(1.f, __fadd_rn(b0, EPS));
    const float w1r = __fdiv_rn(1.f, __fadd_rn(b1, EPS));
    const float w2r = __fdiv_rn(1.f, __fadd_rn(b2, EPS));
    const float sum = __fadd_rn(__fadd_rn(w0r, w1r), w2r);
    const float w0 = __fdiv_rn(w0r, sum);
    const float w1 = __fdiv_rn(w1r, sum);
    const float w2 = __fdiv_rn(w2r, sum);
    const int j0 = (int)(unsigned)(k0 & 0xffffffffu);
    const int j1 = (int)(unsigned)(k1 & 0xffffffffu);
    const int j2 = (int)(unsigned)(k2 & 0xffffffffu);

    // interpolation: whole wave on this query's row, float2 per lane (C even)
    const float2* f0 = (const float2*)(feat + (size_t)j0 * C);
    const float2* f1 = (const float2*)(feat + (size_t)j1 * C);
    const float2* f2 = (const float2*)(feat + (size_t)j2 * C);
    float2* o = (float2*)(out + (size_t)orig * C);
    const int nc2 = C >> 1;
    for (int cc = lane; cc < nc2; cc += 64) {
        float2 a = f0[cc], b = f1[cc], d = f2[cc];
        o[cc] = make_float2(w0 * a.x + w1 * b.x + w2 * d.x,
                            w0 * a.y + w1 * b.y + w2 * d.y);
    }
}

// ---------------- dense fallback (validated R7 path) ----------------
#define NW 16
__global__ void knn_preproc(const float* __restrict__ sp, float4* __restrict__ sp4, int N) {
    int j = blockIdx.x * blockDim.x + threadIdx.x;
    if (j < N) {
        float x = sp[3 * j + 0], y = sp[3 * j + 1], z = sp[3 * j + 2];
        float s2 = __fadd_rn(__fadd_rn(__fmul_rn(x, x), __fmul_rn(y, y)), __fmul_rn(z, z));
        sp4[j] = make_float4(-2.f * x, -2.f * y, -2.f * z, s2);
    }
}
__device__ __forceinline__ void insert3_bl(float d, int j,
                                           float& d0, float& d1, float& d2,
                                           int& i0, int& i1, int& i2) {
    const bool c0 = d < d0, c1 = d < d1, c2 = d < d2;
    const float nd2 = c1 ? d1 : (c2 ? d : d2);
    const int   ni2 = c1 ? i1 : (c2 ? j : i2);
    const float nd1 = c0 ? d0 : (c1 ? d : d1);
    const int   ni1 = c0 ? i0 : (c1 ? j : i1);
    const float nd0 = c0 ? d : d0;
    const int   ni0 = c0 ? j : i0;
    d0 = nd0; d1 = nd1; d2 = nd2;
    i0 = ni0; i1 = ni1; i2 = ni2;
}
#define SCORE_INSERT(p, jv) do {                                          \
    float _a = fmaf((p).z, tz, fmaf((p).y, ty, __fmul_rn((p).x, tx)));    \
    float _d = __fadd_rn(__fadd_rn(t2, _a), (p).w);                       \
    if (__any(_d < d2))                                                   \
        insert3_bl(_d, (jv), d0, d1, d2, i0, i1, i2);                     \
} while (0)
__global__ __launch_bounds__(1024, 8) void knn_dense(
    const float4* __restrict__ sp4, const float* __restrict__ feat,
    const float* __restrict__ tp, float* __restrict__ out,
    int N, int M, int C) {
    __shared__ float s_d[NW][3][64];
    __shared__ int   s_i[NW][3][64];
    __shared__ float s_w[3][64];
    __shared__ int   s_j[3][64];
    const int tid  = threadIdx.x;
    const int lane = tid & 63;
    const int wave = __builtin_amdgcn_readfirstlane(tid >> 6);
    const int mbase = blockIdx.x * 64;
    const int m = mbase + lane;
    float tx = 0.f, ty = 0.f, tz = 0.f;
    if (m < M) { tx = tp[3 * m + 0]; ty = tp[3 * m + 1]; tz = tp[3 * m + 2]; }
    const float t2 = __fadd_rn(__fadd_rn(__fmul_rn(tx, tx), __fmul_rn(ty, ty)),
                               __fmul_rn(tz, tz));
    float d0 = FMAXV, d1 = FMAXV, d2 = FMAXV;
    int   i0 = 0,     i1 = 0,     i2 = 0;
    const int chunk = (N + NW - 1) / NW;
    const int jbeg = wave * chunk;
    const int jend = min(jbeg + chunk, N);
    int j = jbeg;
    for (; j + 8 <= jend; j += 8) {
        float4 p0 = sp4[j + 0], p1 = sp4[j + 1], p2 = sp4[j + 2], p3 = sp4[j + 3];
        float4 p4 = sp4[j + 4], p5 = sp4[j + 5], p6 = sp4[j + 6], p7 = sp4[j + 7];
        SCORE_INSERT(p0, j + 0); SCORE_INSERT(p1, j + 1);
        SCORE_INSERT(p2, j + 2); SCORE_INSERT(p3, j + 3);
        SCORE_INSERT(p4, j + 4); SCORE_INSERT(p5, j + 5);
        SCORE_INSERT(p6, j + 6); SCORE_INSERT(p7, j + 7);
    }
    for (; j < jend; ++j) { float4 p = sp4[j]; SCORE_INSERT(p, j); }
    s_d[wave][0][lane] = d0; s_d[wave][1][lane] = d1; s_d[wave][2][lane] = d2;
    s_i[wave][0][lane] = i0; s_i[wave][1][lane] = i1; s_i[wave][2][lane] = i2;
    __syncthreads();
    if (wave == 0) {
        float b0 = FMAXV, b1 = FMAXV, b2 = FMAXV;
        int   j0 = 0,     j1 = 0,     j2 = 0;
        #pragma unroll
        for (int w = 0; w < NW; ++w)
            #pragma unroll
            for (int k = 0; k < 3; ++k)
                insert3_bl(s_d[w][k][lane], s_i[w][k][lane], b0, b1, b2, j0, j1, j2);
        float w0 = __fdiv_rn(1.f, __fadd_rn(b0, EPS));
        float w1 = __fdiv_rn(1.f, __fadd_rn(b1, EPS));
        float w2 = __fdiv_rn(1.f, __fadd_rn(b2, EPS));
        float sum = __fadd_rn(__fadd_rn(w0, w1), w2);
        s_w[0][lane] = __fdiv_rn(w0, sum);
        s_w[1][lane] = __fdiv_rn(w1, sum);
        s_w[2][lane] = __fdiv_rn(w2, sum);
        s_j[0][lane] = j0; s_j[1][lane] = j1; s_j[2][lane] = j2;
    }
    __syncthreads();
    const int tm = tid >> 4;
    const int qq = tid & 15;
    const int gm = mbase + tm;
    if (gm < M) {
        const int nv = C >> 6;
        const float w0 = s_w[0][tm], w1 = s_w[1][tm], w2 = s_w[2][tm];
        const float4* f0 = (const float4*)(feat + (size_t)s_j[0][tm] * C) + qq * nv;
        const float4* f1 = (const float4*)(feat + (size_t)s_j[1][tm] * C) + qq * nv;
        const float4* f2 = (const float4*)(feat + (size_t)s_j[2][tm] * C) + qq * nv;
        float4* o = (float4*)(out + (size_t)gm * C) + qq * nv;
        for (int r = 0; r < nv; ++r) {
            float4 a = f0[r], b = f1[r], c = f2[r];
            float4 v;
            v.x = w0 * a.x + w1 * b.x + w2 * c.x;
            v.y = w0 * a.y + w1 * b.y + w2 * c.y;
            v.z = w0 * a.z + w1 * b.z + w2 * c.z;
            v.w = w0 * a.w + w1 * b.w + w2 * c.w;
            o[r] = v;
        }
    }
}

// ---------------- host ----------------
static inline size_t align256(size_t x) { return (x + 255) & ~(size_t)255; }

extern "C" void kernel_launch(void* const* d_in, const int* in_sizes, int n_in,
                              void* d_out, int out_size, void* d_ws, size_t ws_size,
                              hipStream_t stream) {
    const float* sp   = (const float*)d_in[0];  // source_points [N,3]
    const float* feat = (const float*)d_in[1];  // source_features [N,C]
    const float* tp   = (const float*)d_in[2];  // target_points [M,3]
    float* out = (float*)d_out;                 // [M,C] fp32

    const int N = in_sizes[0] / 3;
    const int C = in_sizes[1] / N;
    const int M = in_sizes[2] / 3;

    // ws layout (2-D windowed wave-per-query path)
    size_t oScnt  = 0;                                        // NC2 ints
    size_t oQcnt  = oScnt + (size_t)NC2 * 4;                  // NC2 ints (adjacent -> one memset)
    size_t oSoffs = align256(oQcnt + (size_t)NC2 * 4);        // NC2+1 ints
    size_t oQoffs = align256(oSoffs + (size_t)(NC2 + 1) * 4); // NC2+1 ints
    size_t oSpts  = align256(oQoffs + (size_t)(NC2 + 1) * 4); // N float4
    size_t oSidx  = align256(oSpts + (size_t)N * 16);         // N ints
    size_t oQpts  = align256(oSidx + (size_t)N * 4);          // M float4
    size_t need   = oQpts + (size_t)M * 16;

    if (ws_size >= need && (C & 1) == 0 && N >= 256) {
        char* ws = (char*)d_ws;
        int*    scnt  = (int*)(ws + oScnt);
        int*    qcnt  = (int*)(ws + oQcnt);
        int*    soffs = (int*)(ws + oSoffs);
        int*    qoffs = (int*)(ws + oQoffs);
        float4* spts  = (float4*)(ws + oSpts);
        int*    sidxp = (int*)(ws + oSidx);
        float4* qpts  = (float4*)(ws + oQpts);

        hipMemsetAsync(scnt, 0, (size_t)2 * NC2 * 4, stream);
        int nmBlocks = (N + M + 255) / 256;
        k_hist2D<<<nmBlocks, 256, 0, stream>>>(sp, N, tp, M, scnt, qcnt);
        k_scan4k<<<2, 1024, 0, stream>>>(scnt, qcnt, soffs, qoffs);
        k_scat2D<<<nmBlocks, 256, 0, stream>>>(sp, N, tp, M, scnt, spts, sidxp, qcnt, qpts);
        k_knn_w2<<<(M + 3) / 4, 256, 0, stream>>>(spts, sidxp, soffs, qpts, feat, out, N, M, C);
    } else {
        // dense fallback (validated R7)
        float4* sp4 = (float4*)d_ws;
        knn_preproc<<<(N + 255) / 256, 256, 0, stream>>>(sp, sp4, N);
        knn_dense<<<(M + 63) / 64, 1024, 0, stream>>>(sp4, feat, tp, out, N, M, C);
    }
}